// Round 5
// baseline (282.562 us; speedup 1.0000x reference)
//
#include <hip/hip_runtime.h>
#include <hip/hip_bf16.h>

typedef __attribute__((ext_vector_type(8))) short short8;
typedef __attribute__((ext_vector_type(4))) float floatx4;

#define N_ROWS   16384
#define IN_DIM   512
#define OUT_DIM  512
#define K_SPLINE 4096
#define K_TOT    4608
#define NKT      (K_TOT / 64)    /* 72 k-tiles of 64 */
#define NSPL     (K_SPLINE / 64) /* 64 spline k-tiles */
#define NKTILE   (K_TOT / 32)    /* 144 */
#define L2E      1.4426950408889634f
#define C2E      0.13533528323661270f   /* exp(-2) */

__device__ __forceinline__ unsigned short f2bf(float f) {
    unsigned int u = __float_as_uint(f);
    unsigned int r = u + 0x7FFFu + ((u >> 16) & 1u);
    return (unsigned short)(r >> 16);
}

// truncating pack: two fp32 -> two bf16 in one v_perm_b32 (no rounding adds).
// A-side only; B is rounded once in prep. Error budget: <=2x RTNE quant noise.
__device__ __forceinline__ unsigned packtrunc(float f0, float f1) {
    return __builtin_amdgcn_perm(__float_as_uint(f1), __float_as_uint(f0), 0x07060302);
}

// 8 Gaussian-RBF basis values of one x, straight into an MFMA A-fragment.
// u = 1.75x+3.5 ; b_j = exp(-(u-j)^2) via b_{j+1}=b_j*r, r_{j+1}=r_j*exp(-2)
__device__ __forceinline__ short8 gen_basis(float X) {
    const float u = fmaf(1.75f, X, 3.5f);
    float b = __builtin_amdgcn_exp2f(-(u * u) * L2E);            // exp(-u^2)
    float r = __builtin_amdgcn_exp2f(fmaf(2.0f * L2E, u, -L2E)); // exp(2u-1)
    float v[8];
    v[0] = b;
    #pragma unroll
    for (int j = 1; j < 8; ++j) { b *= r; r *= C2E; v[j] = b; }
    union { unsigned d[4]; short8 s; } o;
    o.d[0] = packtrunc(v[0], v[1]);
    o.d[1] = packtrunc(v[2], v[3]);
    o.d[2] = packtrunc(v[4], v[5]);
    o.d[3] = packtrunc(v[6], v[7]);
    return o.s;
}

// silu of 8 consecutive x -> MFMA A-fragment
__device__ __forceinline__ short8 gen_silu(const float* p) {
    const float4 a0 = *reinterpret_cast<const float4*>(p);
    const float4 a1 = *reinterpret_cast<const float4*>(p + 4);
    const float f[8] = {a0.x, a0.y, a0.z, a0.w, a1.x, a1.y, a1.z, a1.w};
    float s[8];
    #pragma unroll
    for (int j = 0; j < 8; ++j)
        s[j] = f[j] * __builtin_amdgcn_rcpf(
            1.0f + __builtin_amdgcn_exp2f(-f[j] * L2E));
    union { unsigned d[4]; short8 v; } o;
    o.d[0] = packtrunc(s[0], s[1]);
    o.d[1] = packtrunc(s[2], s[3]);
    o.d[2] = packtrunc(s[4], s[5]);
    o.d[3] = packtrunc(s[6], s[7]);
    return o.v;
}

// ---------------------------------------------------------------------------
// prep: write B in MFMA B-fragment-tiled layout (unchanged from R4).
// Btf frag index = (ct*NKTILE + ktile)*64 + lane ; frag elem j:
//   n = ct*16 + (lane&15), k = ktile*32 + (lane>>4)*8 + j
// ---------------------------------------------------------------------------
__global__ __launch_bounds__(256) void prep_kernel(
    const float* __restrict__ sw, const float* __restrict__ bw,
    unsigned short* __restrict__ Btf)
{
    const int t     = threadIdx.x;
    const int lane  = t & 63;
    const int ktile = blockIdx.x * 4 + (t >> 6);
    const int ct    = blockIdx.y;
    const int mn    = lane & 15, q = lane >> 4;
    const int n     = ct * 16 + mn;
    const int kbase = ktile * 32 + q * 8;
    short8 v;
    if (kbase < K_SPLINE) {
        #pragma unroll
        for (int j = 0; j < 8; ++j)
            v[j] = (short)f2bf(sw[(size_t)(kbase + j) * OUT_DIM + n]);
    } else {
        #pragma unroll
        for (int j = 0; j < 8; ++j)
            v[j] = (short)f2bf(bw[(size_t)n * IN_DIM + (kbase + j - K_SPLINE)]);
    }
    reinterpret_cast<short8*>(Btf)[(size_t)(ct * NKTILE + ktile) * 64 + lane] = v;
}

// B fragment load: direct global -> registers (MFMA B layout, coalesced 16B/lane)
template<bool PREP>
__device__ __forceinline__ void load_bfrags(short8 dst[4][2], const short8* __restrict__ Bf,
                                            const size_t* bbase, int kt,
                                            const float* __restrict__ sw,
                                            const float* __restrict__ bw,
                                            int col0, int lane)
{
    if (PREP) {
        #pragma unroll
        for (int nt = 0; nt < 4; ++nt)
            #pragma unroll
            for (int s = 0; s < 2; ++s)
                dst[nt][s] = Bf[bbase[nt] + (size_t)(kt * 2 + s) * 64];
    } else {
        const int mn = lane & 15, q = lane >> 4;
        #pragma unroll
        for (int nt = 0; nt < 4; ++nt) {
            const int n = col0 + nt * 16 + mn;
            #pragma unroll
            for (int s = 0; s < 2; ++s) {
                short8 v;
                #pragma unroll
                for (int j = 0; j < 8; ++j) {
                    const int k = (kt * 2 + s) * 32 + q * 8 + j;
                    const float val = (k < K_SPLINE)
                        ? sw[(size_t)k * OUT_DIM + n]
                        : bw[(size_t)n * IN_DIM + (k - K_SPLINE)];
                    v[j] = (short)f2bf(val);
                }
                dst[nt][s] = v;
            }
        }
    }
}

// ---------------------------------------------------------------------------
// Fused KAN, barrier-free: NO LDS. Each wave owns a 64x64 output tile.
//   A fragments generated in-register (basis/silu straight into MFMA layout).
//   B fragments loaded global->register with 1-iter compile-time dbuf.
//   grid 512 blocks x 4 waves; bid&1 = column half (XCD-L2 affinity).
// ---------------------------------------------------------------------------
template<bool PREP>
__global__ __launch_bounds__(256, 2) void kan_kernel(
    const float* __restrict__ x,
    const unsigned short* __restrict__ Btf,
    const float* __restrict__ sw,
    const float* __restrict__ bw,
    const float* __restrict__ bias,
    float* __restrict__ out)
{
    const int tid  = threadIdx.x;
    const int wv   = tid >> 6;
    const int lane = tid & 63;
    const int q    = lane >> 4;
    const int mn   = lane & 15;
    const int bid  = blockIdx.x;
    const int half = bid & 1;                 // col half; == XCD parity for L2 affinity
    const int row0 = (bid >> 1) * 64;
    const int col0 = half * 256 + wv * 64;

    const short8* Bf = reinterpret_cast<const short8*>(Btf);
    size_t bbase[4];
    #pragma unroll
    for (int nt = 0; nt < 4; ++nt)
        bbase[nt] = (size_t)(((col0 >> 4) + nt) * NKTILE) * 64 + lane;

    // per-thread x row pointers (row = row0 + mt*16 + mn)
    const float* xr[4];
    #pragma unroll
    for (int mt = 0; mt < 4; ++mt)
        xr[mt] = x + (size_t)(row0 + mt * 16 + mn) * IN_DIM;

    floatx4 acc[4][4];
    #pragma unroll
    for (int i = 0; i < 4; ++i)
        #pragma unroll
        for (int j = 0; j < 4; ++j)
            acc[i][j] = (floatx4){0.f, 0.f, 0.f, 0.f};

    short8 bb[2][4][2];     // B frag double buffer (compile-time indexed!)
    float  xs[2][4][2];     // spline x prefetch [buf][mt][s]

    // prologue
    load_bfrags<PREP>(bb[0], Bf, bbase, 0, sw, bw, col0, lane);
    #pragma unroll
    for (int mt = 0; mt < 4; ++mt)
        #pragma unroll
        for (int s = 0; s < 2; ++s)
            xs[0][mt][s] = xr[mt][s * 4 + q];

    // ---------------- spline region: kt 0..63 ----------------
    for (int ktb = 0; ktb < NSPL; ktb += 2) {
        #pragma unroll
        for (int h = 0; h < 2; ++h) {
            const int kt = ktb + h;
            const int cur = h, nxt = h ^ 1;
            load_bfrags<PREP>(bb[nxt], Bf, bbase, kt + 1, sw, bw, col0, lane);
            if (kt + 1 < NSPL) {
                #pragma unroll
                for (int mt = 0; mt < 4; ++mt)
                    #pragma unroll
                    for (int s = 0; s < 2; ++s)
                        xs[nxt][mt][s] = xr[mt][(kt + 1) * 8 + s * 4 + q];
            }
            #pragma unroll
            for (int s = 0; s < 2; ++s)
                #pragma unroll
                for (int mt = 0; mt < 4; ++mt) {
                    const short8 af = gen_basis(xs[cur][mt][s]);
                    #pragma unroll
                    for (int nt = 0; nt < 4; ++nt)
                        acc[mt][nt] = __builtin_amdgcn_mfma_f32_16x16x32_bf16(
                            af, bb[cur][nt][s], acc[mt][nt], 0, 0, 0);
                }
        }
    }

    // ---------------- silu region: kt 64..71 ----------------
    for (int ktb = NSPL; ktb < NKT; ktb += 2) {
        #pragma unroll
        for (int h = 0; h < 2; ++h) {
            const int kt = ktb + h;
            const int cur = h, nxt = h ^ 1;
            if (kt + 1 < NKT)
                load_bfrags<PREP>(bb[nxt], Bf, bbase, kt + 1, sw, bw, col0, lane);
            #pragma unroll
            for (int s = 0; s < 2; ++s)
                #pragma unroll
                for (int mt = 0; mt < 4; ++mt) {
                    const short8 af = gen_silu(xr[mt] + (kt - NSPL) * 64 + s * 32 + q * 8);
                    #pragma unroll
                    for (int nt = 0; nt < 4; ++nt)
                        acc[mt][nt] = __builtin_amdgcn_mfma_f32_16x16x32_bf16(
                            af, bb[cur][nt][s], acc[mt][nt], 0, 0, 0);
                }
        }
    }

    // ---------------- epilogue: + bias, store fp32 ----------------
    #pragma unroll
    for (int nt = 0; nt < 4; ++nt) {
        const int col = col0 + nt * 16 + mn;
        const float bv = bias[col];
        #pragma unroll
        for (int mt = 0; mt < 4; ++mt) {
            const int rb = row0 + mt * 16 + q * 4;
            #pragma unroll
            for (int e = 0; e < 4; ++e)
                out[(size_t)(rb + e) * OUT_DIM + col] = acc[mt][nt][e] + bv;
        }
    }
}

extern "C" void kernel_launch(void* const* d_in, const int* in_sizes, int n_in,
                              void* d_out, int out_size, void* d_ws, size_t ws_size,
                              hipStream_t stream)
{
    const float* x    = (const float*)d_in[0];
    // d_in[1] = grid (linspace(-2,2,8)) — folded into constants
    const float* sw   = (const float*)d_in[2];
    const float* bw   = (const float*)d_in[3];
    const float* bias = (const float*)d_in[4];
    float* out = (float*)d_out;

    const size_t bt_bytes = (size_t)OUT_DIM * K_TOT * sizeof(unsigned short);
    if (ws_size >= bt_bytes) {
        unsigned short* Btf = (unsigned short*)d_ws;
        prep_kernel<<<dim3(NKTILE / 4, OUT_DIM / 16), 256, 0, stream>>>(sw, bw, Btf);
        kan_kernel<true><<<dim3(512), 256, 0, stream>>>(x, Btf, sw, bw, bias, out);
    } else {
        kan_kernel<false><<<dim3(512), 256, 0, stream>>>(x, nullptr, sw, bw, bias, out);
    }
}

// Round 6
// 218.435 us; speedup vs baseline: 1.2936x; 1.2936x over previous
//
#include <hip/hip_runtime.h>
#include <hip/hip_bf16.h>

typedef __attribute__((ext_vector_type(8))) short short8;
typedef __attribute__((ext_vector_type(4))) float floatx4;

#define N_ROWS   16384
#define IN_DIM   512
#define OUT_DIM  512
#define K_SPLINE 4096
#define K_TOT    4608
#define NKT      72              /* k-tiles of 64 */
#define KHT      36              /* k-tiles per K-half */
#define NSPL     64              /* spline k-tiles */
#define NKTILE   144             /* 32-wide k-tiles */
#define L2E      1.4426950408889634f
#define C2E      0.13533528323661270f   /* exp(-2) */

__device__ __forceinline__ unsigned short f2bf(float f) {
    unsigned int u = __float_as_uint(f);
    unsigned int r = u + 0x7FFFu + ((u >> 16) & 1u);
    return (unsigned short)(r >> 16);
}

// truncating pack: two fp32 -> two bf16 in one v_perm_b32 (A-side only; B rounded in prep)
__device__ __forceinline__ unsigned packtrunc(float f0, float f1) {
    return __builtin_amdgcn_perm(__float_as_uint(f1), __float_as_uint(f0), 0x07060302);
}

// ---------------------------------------------------------------------------
// prep: B in MFMA B-fragment-tiled layout.
// frag idx = (ct*NKTILE + kt32)*64 + lane ; elem j:
//   n = ct*16 + (lane&15), k = kt32*32 + (lane>>4)*8 + j
// ---------------------------------------------------------------------------
__global__ __launch_bounds__(256) void prep_kernel(
    const float* __restrict__ sw, const float* __restrict__ bw,
    unsigned short* __restrict__ Btf)
{
    const int t     = threadIdx.x;
    const int lane  = t & 63;
    const int kt32  = blockIdx.x * 4 + (t >> 6);
    const int ct    = blockIdx.y;
    const int mn    = lane & 15, q = lane >> 4;
    const int n     = ct * 16 + mn;
    const int kbase = kt32 * 32 + q * 8;
    short8 v;
    if (kbase < K_SPLINE) {
        #pragma unroll
        for (int j = 0; j < 8; ++j)
            v[j] = (short)f2bf(sw[(size_t)(kbase + j) * OUT_DIM + n]);
    } else {
        #pragma unroll
        for (int j = 0; j < 8; ++j)
            v[j] = (short)f2bf(bw[(size_t)n * IN_DIM + (kbase + j - K_SPLINE)]);
    }
    reinterpret_cast<short8*>(Btf)[(size_t)(ct * NKTILE + kt32) * 64 + lane] = v;
}

// ---------------------------------------------------------------------------
// A staging into swizzled LDS (64 rows x 64 bf16, 16B block ^ (row&7))
// ---------------------------------------------------------------------------
__device__ __forceinline__ void stage_spline(unsigned short* buf, int rowA, int colq,
                                             float2 xv)
{
    unsigned short* arow = buf + rowA * 64;
    #pragma unroll
    for (int e = 0; e < 2; ++e) {
        const float X = e ? xv.y : xv.x;
        const float u = fmaf(1.75f, X, 3.5f);
        float b = __builtin_amdgcn_exp2f(-(u * u) * L2E);            // exp(-u^2)
        float r = __builtin_amdgcn_exp2f(fmaf(2.0f * L2E, u, -L2E)); // exp(2u-1)
        float v[8];
        v[0] = b;
        #pragma unroll
        for (int j = 1; j < 8; ++j) { b *= r; r *= C2E; v[j] = b; }
        uint4 p;
        p.x = packtrunc(v[0], v[1]);
        p.y = packtrunc(v[2], v[3]);
        p.z = packtrunc(v[4], v[5]);
        p.w = packtrunc(v[6], v[7]);
        const int blk = (colq * 2 + e) ^ (rowA & 7);
        *reinterpret_cast<uint4*>(arow + blk * 8) = p;
    }
}

__device__ __forceinline__ void stage_silu(unsigned short* buf, int rowA, int colq,
                                           const float* xrow, int ktg)
{
    unsigned short* arow = buf + rowA * 64;
    const float* xs = xrow + (ktg - NSPL) * 64 + colq * 16;
    const float4 a0 = *reinterpret_cast<const float4*>(xs);
    const float4 a1 = *reinterpret_cast<const float4*>(xs + 4);
    const float4 a2 = *reinterpret_cast<const float4*>(xs + 8);
    const float4 a3 = *reinterpret_cast<const float4*>(xs + 12);
    const float f[16] = {a0.x, a0.y, a0.z, a0.w, a1.x, a1.y, a1.z, a1.w,
                         a2.x, a2.y, a2.z, a2.w, a3.x, a3.y, a3.z, a3.w};
    float s[16];
    #pragma unroll
    for (int j = 0; j < 16; ++j)
        s[j] = f[j] * __builtin_amdgcn_rcpf(
            1.0f + __builtin_amdgcn_exp2f(-f[j] * L2E));
    #pragma unroll
    for (int e = 0; e < 2; ++e) {
        uint4 p;
        p.x = packtrunc(s[e * 8 + 0], s[e * 8 + 1]);
        p.y = packtrunc(s[e * 8 + 2], s[e * 8 + 3]);
        p.z = packtrunc(s[e * 8 + 4], s[e * 8 + 5]);
        p.w = packtrunc(s[e * 8 + 6], s[e * 8 + 7]);
        const int blk = (colq * 2 + e) ^ (rowA & 7);
        *reinterpret_cast<uint4*>(arow + blk * 8) = p;
    }
}

// B fragment load for one 32-k tile: 4 frags (one per nt)
template<bool PREP>
__device__ __forceinline__ void loadB(short8 dst[4], const short8* __restrict__ bfp,
                                      int kt32,
                                      const float* __restrict__ sw,
                                      const float* __restrict__ bw,
                                      int col0, int lane)
{
    if (PREP) {
        #pragma unroll
        for (int nt = 0; nt < 4; ++nt)
            dst[nt] = bfp[(size_t)nt * NKTILE * 64 + (size_t)kt32 * 64];
    } else {
        const int mn = lane & 15, q = lane >> 4;
        #pragma unroll
        for (int nt = 0; nt < 4; ++nt) {
            const int n = col0 + nt * 16 + mn;
            short8 v;
            #pragma unroll
            for (int j = 0; j < 8; ++j) {
                const int k = kt32 * 32 + q * 8 + j;
                const float val = (k < K_SPLINE)
                    ? sw[(size_t)k * OUT_DIM + n]
                    : bw[(size_t)n * IN_DIM + (k - K_SPLINE)];
                v[j] = (short)f2bf(val);
            }
            dst[nt] = v;
        }
    }
}

// ---------------------------------------------------------------------------
// Fused KAN, intra-block split-K x2.
//   512 threads = 8 waves. kh = tid>>8 (k-half), wn = wave&3 (64-col group).
//   Waves 0-3: k 0..2303 ; waves 4-7: k 2304..4607 ; same 64x256 output tile.
//   A: generated -> per-half LDS dbuf (one barrier/iter, 36 iters).
//   B: direct global->register, per-s single-slot reload-after-use.
//   Epilogue: kh=1 partials through LDS (reusing A bufs) -> kh=0 adds + stores.
//   4 waves/SIMD occupancy (vs R4's 2) to hide barrier/L2 waits.
// ---------------------------------------------------------------------------
template<bool PREP>
__global__ __launch_bounds__(512, 4) void kan_kernel(
    const float* __restrict__ x,
    const unsigned short* __restrict__ Btf,
    const float* __restrict__ sw,
    const float* __restrict__ bw,
    const float* __restrict__ bias,
    float* __restrict__ out)
{
    __shared__ unsigned short Als[2][2][64 * 64];   // [kh][buf] = 32 KB total

    const int tid  = threadIdx.x;
    const int kh   = tid >> 8;                 // k-half
    const int wn   = (tid >> 6) & 3;           // 64-col group
    const int lane = tid & 63;
    const int q    = lane >> 4;
    const int mn   = lane & 15;
    const int bid  = blockIdx.x;
    const int row0 = (bid >> 1) * 64;
    const int col0 = (bid & 1) * 256 + wn * 64;   // bid&1: XCD-parity col half

    // A staging role: th = tid within half (0..255)
    const int th   = tid & 255;
    const int rowA = th >> 2;
    const int colq = th & 3;
    const float* xrowA = x + (size_t)(row0 + rowA) * IN_DIM;

    const short8* Bf  = reinterpret_cast<const short8*>(Btf);
    const short8* bfp = Bf + (size_t)(col0 >> 4) * NKTILE * 64 + lane;

    const int base = kh * KHT;

    floatx4 acc[4][4];
    #pragma unroll
    for (int i = 0; i < 4; ++i)
        #pragma unroll
        for (int j = 0; j < 4; ++j)
            acc[i][j] = (floatx4){0.f, 0.f, 0.f, 0.f};

    short8 b0[4], b1[4];

    // ---------------- prologue ----------------
    {
        const float2 xv = *reinterpret_cast<const float2*>(xrowA + base * 8 + colq * 2);
        stage_spline(&Als[kh][0][0], rowA, colq, xv);   // tile base is spline for both halves
    }
    loadB<PREP>(b0, bfp, base * 2 + 0, sw, bw, col0, lane);
    loadB<PREP>(b1, bfp, base * 2 + 1, sw, bw, col0, lane);
    float2 xp = *reinterpret_cast<const float2*>(xrowA + (base + 1) * 8 + colq * 2);
    __syncthreads();

    // ---------------- main loop: 36 iters, one barrier each ----------------
    for (int ktb = 0; ktb < KHT; ktb += 2) {
        #pragma unroll
        for (int h = 0; h < 2; ++h) {            // literal dbuf selectors
            const int ktl = ktb + h;
            const int ktg = base + ktl;
            const unsigned short* Acur = &Als[kh][h][0];
            unsigned short*       Anxt = &Als[kh][h ^ 1][0];

            // stage A for next tile
            if (ktl + 1 < KHT) {
                if (ktg + 1 < NSPL) {
                    stage_spline(Anxt, rowA, colq, xp);
                    if (ktl + 2 < KHT && ktg + 2 < NSPL)
                        xp = *reinterpret_cast<const float2*>(
                            xrowA + (ktg + 2) * 8 + colq * 2);
                } else {
                    stage_silu(Anxt, rowA, colq, xrowA, ktg + 1);
                }
            }

            // MFMA s=0, then reload b0 for next tile
            {
                short8 af[4];
                #pragma unroll
                for (int mt = 0; mt < 4; ++mt) {
                    const int r = mt * 16 + mn;
                    af[mt] = *reinterpret_cast<const short8*>(
                        Acur + r * 64 + ((q ^ (r & 7)) * 8));
                }
                #pragma unroll
                for (int mt = 0; mt < 4; ++mt)
                    #pragma unroll
                    for (int nt = 0; nt < 4; ++nt)
                        acc[mt][nt] = __builtin_amdgcn_mfma_f32_16x16x32_bf16(
                            af[mt], b0[nt], acc[mt][nt], 0, 0, 0);
            }
            if (ktl + 1 < KHT)
                loadB<PREP>(b0, bfp, (ktg + 1) * 2 + 0, sw, bw, col0, lane);

            // MFMA s=1, then reload b1 for next tile
            {
                short8 af[4];
                #pragma unroll
                for (int mt = 0; mt < 4; ++mt) {
                    const int r = mt * 16 + mn;
                    af[mt] = *reinterpret_cast<const short8*>(
                        Acur + r * 64 + (((4 + q) ^ (r & 7)) * 8));
                }
                #pragma unroll
                for (int mt = 0; mt < 4; ++mt)
                    #pragma unroll
                    for (int nt = 0; nt < 4; ++nt)
                        acc[mt][nt] = __builtin_amdgcn_mfma_f32_16x16x32_bf16(
                            af[mt], b1[nt], acc[mt][nt], 0, 0, 0);
            }
            if (ktl + 1 < KHT)
                loadB<PREP>(b1, bfp, (ktg + 1) * 2 + 1, sw, bw, col0, lane);

            __syncthreads();
        }
    }

    // ---------------- split-K reduction through LDS (reuse Als, 32 KB) -------
    float* red = reinterpret_cast<float*>(&Als[0][0][0]);   // 8192 floats
    #pragma unroll
    for (int r = 0; r < 2; ++r) {
        __syncthreads();
        if (kh == 1) {
            #pragma unroll
            for (int mtl = 0; mtl < 2; ++mtl)
                #pragma unroll
                for (int nt = 0; nt < 4; ++nt)
                    *reinterpret_cast<floatx4*>(
                        &red[wn * 2048 + (mtl * 4 + nt) * 256 + lane * 4]) =
                        acc[r * 2 + mtl][nt];
        }
        __syncthreads();
        if (kh == 0) {
            #pragma unroll
            for (int mtl = 0; mtl < 2; ++mtl)
                #pragma unroll
                for (int nt = 0; nt < 4; ++nt) {
                    const floatx4 v = *reinterpret_cast<const floatx4*>(
                        &red[wn * 2048 + (mtl * 4 + nt) * 256 + lane * 4]);
                    acc[r * 2 + mtl][nt] += v;
                }
        }
    }

    // ---------------- epilogue: + bias, store (kh==0 waves only) ----------------
    if (kh == 0) {
        #pragma unroll
        for (int nt = 0; nt < 4; ++nt) {
            const int col = col0 + nt * 16 + mn;
            const float bv = bias[col];
            #pragma unroll
            for (int mt = 0; mt < 4; ++mt) {
                const int rb = row0 + mt * 16 + q * 4;
                #pragma unroll
                for (int e = 0; e < 4; ++e)
                    out[(size_t)(rb + e) * OUT_DIM + col] = acc[mt][nt][e] + bv;
            }
        }
    }
}

extern "C" void kernel_launch(void* const* d_in, const int* in_sizes, int n_in,
                              void* d_out, int out_size, void* d_ws, size_t ws_size,
                              hipStream_t stream)
{
    const float* x    = (const float*)d_in[0];
    // d_in[1] = grid (linspace(-2,2,8)) — folded into constants
    const float* sw   = (const float*)d_in[2];
    const float* bw   = (const float*)d_in[3];
    const float* bias = (const float*)d_in[4];
    float* out = (float*)d_out;

    const size_t bt_bytes = (size_t)OUT_DIM * K_TOT * sizeof(unsigned short);
    if (ws_size >= bt_bytes) {
        unsigned short* Btf = (unsigned short*)d_ws;
        prep_kernel<<<dim3(NKTILE / 4, OUT_DIM / 16), 256, 0, stream>>>(sw, bw, Btf);
        kan_kernel<true><<<dim3(512), 512, 0, stream>>>(x, Btf, sw, bw, bias, out);
    } else {
        kan_kernel<false><<<dim3(512), 512, 0, stream>>>(x, nullptr, sw, bw, bias, out);
    }
}

// Round 7
// 193.799 us; speedup vs baseline: 1.4580x; 1.1271x over previous
//
#include <hip/hip_runtime.h>
#include <hip/hip_bf16.h>

typedef __attribute__((ext_vector_type(8))) short short8;
typedef __attribute__((ext_vector_type(4))) float floatx4;

#define N_ROWS   16384
#define IN_DIM   512
#define OUT_DIM  512
#define K_SPLINE 4096
#define K_TOT    4608
#define NKT      72              /* k-tiles of 64 */
#define KHT      36              /* k-tiles per K-half (split-K x2) */
#define NSPL     64              /* spline k-tiles */
#define NKTILE   144             /* 32-wide k-tiles */
#define L2E      1.4426950408889634f
#define C2E      0.13533528323661270f   /* exp(-2) */

__device__ __forceinline__ unsigned short f2bf(float f) {
    unsigned int u = __float_as_uint(f);
    unsigned int r = u + 0x7FFFu + ((u >> 16) & 1u);
    return (unsigned short)(r >> 16);
}

// truncating pack: two fp32 -> two bf16 in one v_perm_b32 (A-side only; B rounded in prep)
__device__ __forceinline__ unsigned packtrunc(float f0, float f1) {
    return __builtin_amdgcn_perm(__float_as_uint(f1), __float_as_uint(f0), 0x07060302);
}

// ---------------------------------------------------------------------------
// prep: B in MFMA B-fragment-tiled layout.
// frag idx = (ct*NKTILE + kt32)*64 + lane ; elem j:
//   n = ct*16 + (lane&15), k = kt32*32 + (lane>>4)*8 + j
// ---------------------------------------------------------------------------
__global__ __launch_bounds__(256) void prep_kernel(
    const float* __restrict__ sw, const float* __restrict__ bw,
    unsigned short* __restrict__ Btf)
{
    const int t     = threadIdx.x;
    const int lane  = t & 63;
    const int kt32  = blockIdx.x * 4 + (t >> 6);
    const int ct    = blockIdx.y;
    const int mn    = lane & 15, q = lane >> 4;
    const int n     = ct * 16 + mn;
    const int kbase = kt32 * 32 + q * 8;
    short8 v;
    if (kbase < K_SPLINE) {
        #pragma unroll
        for (int j = 0; j < 8; ++j)
            v[j] = (short)f2bf(sw[(size_t)(kbase + j) * OUT_DIM + n]);
    } else {
        #pragma unroll
        for (int j = 0; j < 8; ++j)
            v[j] = (short)f2bf(bw[(size_t)n * IN_DIM + (kbase + j - K_SPLINE)]);
    }
    reinterpret_cast<short8*>(Btf)[(size_t)(ct * NKTILE + kt32) * 64 + lane] = v;
}

// ---------------------------------------------------------------------------
// A staging into swizzled LDS (64 rows x 64 bf16, 16B block ^ (row&7)) — R4 code
// ---------------------------------------------------------------------------
__device__ __forceinline__ void stageA(unsigned short* dst, const float* xrow,
                                       int rowA, int colq, int kt)
{
    unsigned short* arow = dst + rowA * 64;
    if (kt < NSPL) {
        const float2 xv = *reinterpret_cast<const float2*>(xrow + kt * 8 + colq * 2);
        #pragma unroll
        for (int e = 0; e < 2; ++e) {
            const float X = e ? xv.y : xv.x;
            const float u = fmaf(1.75f, X, 3.5f);
            float b = __builtin_amdgcn_exp2f(-(u * u) * L2E);            // exp(-u^2)
            float r = __builtin_amdgcn_exp2f(fmaf(2.0f * L2E, u, -L2E)); // exp(2u-1)
            float v[8];
            v[0] = b;
            #pragma unroll
            for (int j = 1; j < 8; ++j) { b *= r; r *= C2E; v[j] = b; }
            uint4 p;
            p.x = packtrunc(v[0], v[1]);
            p.y = packtrunc(v[2], v[3]);
            p.z = packtrunc(v[4], v[5]);
            p.w = packtrunc(v[6], v[7]);
            const int blk = (colq * 2 + e) ^ (rowA & 7);
            *reinterpret_cast<uint4*>(arow + blk * 8) = p;
        }
    } else {
        const float* xs = xrow + (kt - NSPL) * 64 + colq * 16;
        const float4 a0 = *reinterpret_cast<const float4*>(xs);
        const float4 a1 = *reinterpret_cast<const float4*>(xs + 4);
        const float4 a2 = *reinterpret_cast<const float4*>(xs + 8);
        const float4 a3 = *reinterpret_cast<const float4*>(xs + 12);
        const float f[16] = {a0.x, a0.y, a0.z, a0.w, a1.x, a1.y, a1.z, a1.w,
                             a2.x, a2.y, a2.z, a2.w, a3.x, a3.y, a3.z, a3.w};
        float s[16];
        #pragma unroll
        for (int j = 0; j < 16; ++j)
            s[j] = f[j] * __builtin_amdgcn_rcpf(
                1.0f + __builtin_amdgcn_exp2f(-f[j] * L2E));
        #pragma unroll
        for (int e = 0; e < 2; ++e) {
            uint4 p;
            p.x = packtrunc(s[e * 8 + 0], s[e * 8 + 1]);
            p.y = packtrunc(s[e * 8 + 2], s[e * 8 + 3]);
            p.z = packtrunc(s[e * 8 + 4], s[e * 8 + 5]);
            p.w = packtrunc(s[e * 8 + 6], s[e * 8 + 7]);
            const int blk = (colq * 2 + e) ^ (rowA & 7);
            *reinterpret_cast<uint4*>(arow + blk * 8) = p;
        }
    }
}

// B fragment load: direct global -> registers (MFMA B layout) — R4 code
template<bool PREP>
__device__ __forceinline__ void load_bfrags(short8 dst[4][2], const short8* __restrict__ Bf,
                                            const size_t* bbase, int kt,
                                            const float* __restrict__ sw,
                                            const float* __restrict__ bw,
                                            int col0, int lane)
{
    if (PREP) {
        #pragma unroll
        for (int nt = 0; nt < 4; ++nt)
            #pragma unroll
            for (int s = 0; s < 2; ++s)
                dst[nt][s] = Bf[bbase[nt] + (size_t)(kt * 2 + s) * 64];
    } else {
        const int mn = lane & 15, q = lane >> 4;
        #pragma unroll
        for (int nt = 0; nt < 4; ++nt) {
            const int n = col0 + nt * 16 + mn;
            #pragma unroll
            for (int s = 0; s < 2; ++s) {
                short8 v;
                #pragma unroll
                for (int j = 0; j < 8; ++j) {
                    const int k = (kt * 2 + s) * 32 + q * 8 + j;
                    const float val = (k < K_SPLINE)
                        ? sw[(size_t)k * OUT_DIM + n]
                        : bw[(size_t)n * IN_DIM + (k - K_SPLINE)];
                    v[j] = (short)f2bf(val);
                }
                dst[nt][s] = v;
            }
        }
    }
}

// ---------------------------------------------------------------------------
// Fused KAN — R4 structure, optionally split-K x2 across blocks.
//   blockIdx.x: 512 output tiles (bid>>1 = row tile, bid&1 = col half).
//   blockIdx.y (SPLIT only): k-half. Partials (no bias) -> Pws[kh].
//   Per-wave structure identical to R4 (VGPR ~104 -> 4 blocks/CU possible).
// ---------------------------------------------------------------------------
template<bool PREP, bool SPLIT>
__global__ __launch_bounds__(256, 2) void kan_kernel(
    const float* __restrict__ x,
    const unsigned short* __restrict__ Btf,
    const float* __restrict__ sw,
    const float* __restrict__ bw,
    const float* __restrict__ bias,
    float* __restrict__ out,
    float* __restrict__ Pws)
{
    __shared__ unsigned short Als[2][64 * 64];   // 2 x 8 KB

    const int tid  = threadIdx.x;
    const int wn   = tid >> 6;          // wave 0..3 -> 64-col group
    const int lane = tid & 63;
    const int q    = lane >> 4;
    const int mn   = lane & 15;
    const int bid  = blockIdx.x;
    const int kh   = SPLIT ? blockIdx.y : 0;
    const int row0 = (bid >> 1) * 64;
    const int col0 = (bid & 1) * 256 + wn * 64;
    const int base = kh * KHT;
    const int ITER = SPLIT ? KHT : NKT;

    const int rowA = tid >> 2;          // 0..63
    const int colq = tid & 3;
    const float* xrow = x + (size_t)(row0 + rowA) * IN_DIM;

    size_t bbase[4];
    #pragma unroll
    for (int nt = 0; nt < 4; ++nt)
        bbase[nt] = (size_t)(((col0 >> 4) + nt) * NKTILE) * 64 + lane;
    const short8* Bf = reinterpret_cast<const short8*>(Btf);

    floatx4 acc[4][4];
    #pragma unroll
    for (int i = 0; i < 4; ++i)
        #pragma unroll
        for (int j = 0; j < 4; ++j)
            acc[i][j] = (floatx4){0.f, 0.f, 0.f, 0.f};

    short8 bb[2][4][2];

    // prologue: stage local iter 0 into buffer 0
    stageA(&Als[0][0], xrow, rowA, colq, base);
    load_bfrags<PREP>(bb[0], Bf, bbase, base, sw, bw, col0, lane);
    __syncthreads();

    for (int ktb = 0; ktb < ITER; ktb += 2) {
        #pragma unroll
        for (int half = 0; half < 2; ++half) {       // cur/nxt are literals
            const int ktl = ktb + half;
            const int ktg = base + ktl;
            const int cur = half;
            const int nxt = half ^ 1;
            if (ktl + 1 < ITER) {
                load_bfrags<PREP>(bb[nxt], Bf, bbase, ktg + 1, sw, bw, col0, lane);
                stageA(&Als[nxt][0], xrow, rowA, colq, ktg + 1);
            }
            #pragma unroll
            for (int s = 0; s < 2; ++s) {
                short8 af[4];
                #pragma unroll
                for (int mt = 0; mt < 4; ++mt) {
                    const int r = mt * 16 + mn;
                    af[mt] = *reinterpret_cast<const short8*>(
                        &Als[cur][r * 64 + (((s * 4 + q) ^ (r & 7)) * 8)]);
                }
                #pragma unroll
                for (int mt = 0; mt < 4; ++mt)
                    #pragma unroll
                    for (int nt = 0; nt < 4; ++nt)
                        acc[mt][nt] = __builtin_amdgcn_mfma_f32_16x16x32_bf16(
                            af[mt], bb[cur][nt][s], acc[mt][nt], 0, 0, 0);
            }
            __syncthreads();
        }
    }

    // epilogue
    float* dst = SPLIT ? (Pws + (size_t)kh * N_ROWS * OUT_DIM) : out;
    #pragma unroll
    for (int nt = 0; nt < 4; ++nt) {
        const int col = col0 + nt * 16 + mn;
        const float bv = SPLIT ? 0.0f : bias[col];
        #pragma unroll
        for (int mt = 0; mt < 4; ++mt) {
            const int rb = row0 + mt * 16 + q * 4;
            #pragma unroll
            for (int e = 0; e < 4; ++e)
                dst[(size_t)(rb + e) * OUT_DIM + col] = acc[mt][nt][e] + bv;
        }
    }
}

// out = P0 + P1 + bias  (float4 vectorized, memory-bound)
__global__ __launch_bounds__(256) void reduce_kernel(
    const float* __restrict__ Pws, const float* __restrict__ bias,
    float* __restrict__ out)
{
    const size_t idx = ((size_t)blockIdx.x * 256 + threadIdx.x) * 4;
    const float4 p0 = *reinterpret_cast<const float4*>(Pws + idx);
    const float4 p1 = *reinterpret_cast<const float4*>(Pws + (size_t)N_ROWS * OUT_DIM + idx);
    const float4 bv = *reinterpret_cast<const float4*>(bias + (idx & (OUT_DIM - 1)));
    float4 o;
    o.x = p0.x + p1.x + bv.x;
    o.y = p0.y + p1.y + bv.y;
    o.z = p0.z + p1.z + bv.z;
    o.w = p0.w + p1.w + bv.w;
    *reinterpret_cast<float4*>(out + idx) = o;
}

extern "C" void kernel_launch(void* const* d_in, const int* in_sizes, int n_in,
                              void* d_out, int out_size, void* d_ws, size_t ws_size,
                              hipStream_t stream)
{
    const float* x    = (const float*)d_in[0];
    // d_in[1] = grid (linspace(-2,2,8)) — folded into constants
    const float* sw   = (const float*)d_in[2];
    const float* bw   = (const float*)d_in[3];
    const float* bias = (const float*)d_in[4];
    float* out = (float*)d_out;

    const size_t bt_bytes = (size_t)OUT_DIM * K_TOT * sizeof(unsigned short);
    const size_t p_bytes  = (size_t)2 * N_ROWS * OUT_DIM * sizeof(float);

    if (ws_size >= bt_bytes + p_bytes) {
        unsigned short* Btf = (unsigned short*)d_ws;
        float* Pws = (float*)((char*)d_ws + bt_bytes);
        prep_kernel<<<dim3(NKTILE / 4, OUT_DIM / 16), 256, 0, stream>>>(sw, bw, Btf);
        kan_kernel<true, true><<<dim3(512, 2), 256, 0, stream>>>(
            x, Btf, sw, bw, bias, out, Pws);
        reduce_kernel<<<dim3(N_ROWS * OUT_DIM / 4 / 256), 256, 0, stream>>>(
            Pws, bias, out);
    } else if (ws_size >= bt_bytes) {
        unsigned short* Btf = (unsigned short*)d_ws;
        prep_kernel<<<dim3(NKTILE / 4, OUT_DIM / 16), 256, 0, stream>>>(sw, bw, Btf);
        kan_kernel<true, false><<<dim3(512), 256, 0, stream>>>(
            x, Btf, sw, bw, bias, out, nullptr);
    } else {
        kan_kernel<false, false><<<dim3(512), 256, 0, stream>>>(
            x, nullptr, sw, bw, bias, out, nullptr);
    }
}

// Round 8
// 167.545 us; speedup vs baseline: 1.6865x; 1.1567x over previous
//
#include <hip/hip_runtime.h>
#include <hip/hip_bf16.h>

typedef __attribute__((ext_vector_type(8))) short short8;
typedef __attribute__((ext_vector_type(4))) float floatx4;

#define N_ROWS   16384
#define IN_DIM   512
#define OUT_DIM  512
#define K_SPLINE 4096
#define K_TOT    4608
#define NKT      72              /* 64-k half-periods  */
#define NPER     36              /* 128-k barrier periods */
#define NSPER    32              /* spline periods (4096/128) */
#define NKTILE   144             /* 32-wide k-tiles */
#define L2E      1.4426950408889634f
#define C2E      0.13533528323661270f   /* exp(-2) */

__device__ __forceinline__ unsigned short f2bf(float f) {
    unsigned int u = __float_as_uint(f);
    unsigned int r = u + 0x7FFFu + ((u >> 16) & 1u);
    return (unsigned short)(r >> 16);
}

// truncating pack: two fp32 -> two bf16 in one v_perm_b32 (A-side only; B rounded in prep)
__device__ __forceinline__ unsigned packtrunc(float f0, float f1) {
    return __builtin_amdgcn_perm(__float_as_uint(f1), __float_as_uint(f0), 0x07060302);
}

// ---------------------------------------------------------------------------
// prep: B in MFMA B-fragment-tiled layout.
// frag idx = (ct*NKTILE + kt32)*64 + lane ; elem j:
//   n = ct*16 + (lane&15), k = kt32*32 + (lane>>4)*8 + j
// ---------------------------------------------------------------------------
__global__ __launch_bounds__(256) void prep_kernel(
    const float* __restrict__ sw, const float* __restrict__ bw,
    unsigned short* __restrict__ Btf)
{
    const int t     = threadIdx.x;
    const int lane  = t & 63;
    const int kt32  = blockIdx.x * 4 + (t >> 6);
    const int ct    = blockIdx.y;
    const int mn    = lane & 15, q = lane >> 4;
    const int n     = ct * 16 + mn;
    const int kbase = kt32 * 32 + q * 8;
    short8 v;
    if (kbase < K_SPLINE) {
        #pragma unroll
        for (int j = 0; j < 8; ++j)
            v[j] = (short)f2bf(sw[(size_t)(kbase + j) * OUT_DIM + n]);
    } else {
        #pragma unroll
        for (int j = 0; j < 8; ++j)
            v[j] = (short)f2bf(bw[(size_t)n * IN_DIM + (kbase + j - K_SPLINE)]);
    }
    reinterpret_cast<short8*>(Btf)[(size_t)(ct * NKTILE + kt32) * 64 + lane] = v;
}

// ---------------------------------------------------------------------------
// 8 basis values of one x -> packed uint4 (bf16 x8)
// ---------------------------------------------------------------------------
__device__ __forceinline__ uint4 basis_pack(float X) {
    const float u = fmaf(1.75f, X, 3.5f);
    float b = __builtin_amdgcn_exp2f(-(u * u) * L2E);            // exp(-u^2)
    float r = __builtin_amdgcn_exp2f(fmaf(2.0f * L2E, u, -L2E)); // exp(2u-1)
    float v[8];
    v[0] = b;
    #pragma unroll
    for (int j = 1; j < 8; ++j) { b *= r; r *= C2E; v[j] = b; }
    uint4 p;
    p.x = packtrunc(v[0], v[1]);
    p.y = packtrunc(v[2], v[3]);
    p.z = packtrunc(v[4], v[5]);
    p.w = packtrunc(v[6], v[7]);
    return p;
}

// ---------------------------------------------------------------------------
// Stage one 64x128 A-tile (period p) into swizzled LDS.
// Row stride 128 ushort; 16B blocks, blk ^= (row&15).
// Thread covers row rowA, k-range [colq*32, colq*32+32) of the period.
//   spline period: 4 x-elems = the preloaded float4 xsp
//   silu  period: 32 consecutive x
// ---------------------------------------------------------------------------
__device__ __forceinline__ void stageA128(unsigned short* dst, const float* xrow,
                                          int rowA, int colq, int p, float4 xsp)
{
    unsigned short* arow = dst + rowA * 128;
    if (p < NSPER) {
        const float xv[4] = {xsp.x, xsp.y, xsp.z, xsp.w};
        #pragma unroll
        for (int e = 0; e < 4; ++e) {
            const uint4 pk = basis_pack(xv[e]);
            const int blk = (colq * 4 + e) ^ (rowA & 15);
            *reinterpret_cast<uint4*>(arow + blk * 8) = pk;
        }
    } else {
        const float* xs = xrow + (p - NSPER) * 128 + colq * 32;
        #pragma unroll
        for (int e = 0; e < 4; ++e) {
            const float4 a0 = *reinterpret_cast<const float4*>(xs + e * 8);
            const float4 a1 = *reinterpret_cast<const float4*>(xs + e * 8 + 4);
            const float f[8] = {a0.x, a0.y, a0.z, a0.w, a1.x, a1.y, a1.z, a1.w};
            float s[8];
            #pragma unroll
            for (int j = 0; j < 8; ++j)
                s[j] = f[j] * __builtin_amdgcn_rcpf(
                    1.0f + __builtin_amdgcn_exp2f(-f[j] * L2E));
            uint4 pk;
            pk.x = packtrunc(s[0], s[1]);
            pk.y = packtrunc(s[2], s[3]);
            pk.z = packtrunc(s[4], s[5]);
            pk.w = packtrunc(s[6], s[7]);
            const int blk = (colq * 4 + e) ^ (rowA & 15);
            *reinterpret_cast<uint4*>(arow + blk * 8) = pk;
        }
    }
}

// B fragment load for one 64-k half-period (kt): 4 nt x 2 s — R4 code
template<bool PREP>
__device__ __forceinline__ void load_bfrags(short8 dst[4][2], const short8* __restrict__ Bf,
                                            const size_t* bbase, int kt,
                                            const float* __restrict__ sw,
                                            const float* __restrict__ bw,
                                            int col0, int lane)
{
    if (kt >= NKT) return;
    if (PREP) {
        #pragma unroll
        for (int nt = 0; nt < 4; ++nt)
            #pragma unroll
            for (int s = 0; s < 2; ++s)
                dst[nt][s] = Bf[bbase[nt] + (size_t)(kt * 2 + s) * 64];
    } else {
        const int mn = lane & 15, q = lane >> 4;
        #pragma unroll
        for (int nt = 0; nt < 4; ++nt) {
            const int n = col0 + nt * 16 + mn;
            #pragma unroll
            for (int s = 0; s < 2; ++s) {
                short8 v;
                #pragma unroll
                for (int j = 0; j < 8; ++j) {
                    const int k = (kt * 2 + s) * 32 + q * 8 + j;
                    const float val = (k < K_SPLINE)
                        ? sw[(size_t)k * OUT_DIM + n]
                        : bw[(size_t)n * IN_DIM + (k - K_SPLINE)];
                    v[j] = (short)f2bf(val);
                }
                dst[nt][s] = v;
            }
        }
    }
}

// ---------------------------------------------------------------------------
// Fused KAN — R4 machinery, BK=128: ONE barrier per 128-k period (36 total).
//   512 blocks x 4 waves; wave tile 64x64; A LDS dbuf 2x16KB; B reg dbuf at
//   64-k half-period granularity (literal indices via unrolled hh loop).
// ---------------------------------------------------------------------------
template<bool PREP>
__global__ __launch_bounds__(256, 2) void kan_kernel(
    const float* __restrict__ x,
    const unsigned short* __restrict__ Btf,
    const float* __restrict__ sw,
    const float* __restrict__ bw,
    const float* __restrict__ bias,
    float* __restrict__ out)
{
    __shared__ unsigned short Als[2][64 * 128];   // 2 x 16 KB

    const int tid  = threadIdx.x;
    const int wn   = tid >> 6;          // wave -> 64-col group
    const int lane = tid & 63;
    const int q    = lane >> 4;
    const int mn   = lane & 15;
    const int bid  = blockIdx.x;
    const int row0 = (bid >> 1) * 64;
    const int col0 = (bid & 1) * 256 + wn * 64;   // bid&1: XCD-parity col half

    const int rowA = tid >> 2;          // 0..63
    const int colq = tid & 3;
    const float* xrow = x + (size_t)(row0 + rowA) * IN_DIM;

    size_t bbase[4];
    #pragma unroll
    for (int nt = 0; nt < 4; ++nt)
        bbase[nt] = (size_t)(((col0 >> 4) + nt) * NKTILE) * 64 + lane;
    const short8* Bf = reinterpret_cast<const short8*>(Btf);

    floatx4 acc[4][4];
    #pragma unroll
    for (int i = 0; i < 4; ++i)
        #pragma unroll
        for (int j = 0; j < 4; ++j)
            acc[i][j] = (floatx4){0.f, 0.f, 0.f, 0.f};

    short8 bb[2][4][2];   // B dbuf, literal-indexed via unrolled hh

    // prologue: spline x for p=0, stage p=0, B for kt=0; prefetch x for p=1
    float4 xsp = *reinterpret_cast<const float4*>(xrow + colq * 4);
    stageA128(&Als[0][0], xrow, rowA, colq, 0, xsp);
    load_bfrags<PREP>(bb[0], Bf, bbase, 0, sw, bw, col0, lane);
    xsp = *reinterpret_cast<const float4*>(xrow + 16 + colq * 4);
    __syncthreads();

    for (int p = 0; p < NPER; ++p) {
        const unsigned short* Acur = &Als[p & 1][0];
        unsigned short*       Anxt = &Als[(p & 1) ^ 1][0];

        // B for second half of this period (kt = 2p+1)
        load_bfrags<PREP>(bb[1], Bf, bbase, 2 * p + 1, sw, bw, col0, lane);

        // stage A for period p+1 (overlaps this period's MFMA)
        if (p + 1 < NPER) {
            stageA128(Anxt, xrow, rowA, colq, p + 1, xsp);
            if (p + 2 < NSPER)
                xsp = *reinterpret_cast<const float4*>(
                    xrow + (p + 2) * 16 + colq * 4);
        }

        #pragma unroll
        for (int hh = 0; hh < 2; ++hh) {           // literal B-dbuf index
            #pragma unroll
            for (int s = 0; s < 2; ++s) {
                const int st = hh * 2 + s;
                short8 af[4];
                #pragma unroll
                for (int mt = 0; mt < 4; ++mt) {
                    const int r = mt * 16 + mn;
                    af[mt] = *reinterpret_cast<const short8*>(
                        Acur + r * 128 + (((st * 4 + q) ^ (r & 15)) * 8));
                }
                #pragma unroll
                for (int mt = 0; mt < 4; ++mt)
                    #pragma unroll
                    for (int nt = 0; nt < 4; ++nt)
                        acc[mt][nt] = __builtin_amdgcn_mfma_f32_16x16x32_bf16(
                            af[mt], bb[hh][nt][s], acc[mt][nt], 0, 0, 0);
            }
            // after consuming bb[0], prefetch first half of NEXT period into bb[0]
            if (hh == 0)
                load_bfrags<PREP>(bb[0], Bf, bbase, 2 * p + 2, sw, bw, col0, lane);
        }
        __syncthreads();
    }

    // epilogue: + bias, store fp32
    #pragma unroll
    for (int nt = 0; nt < 4; ++nt) {
        const int col = col0 + nt * 16 + mn;
        const float bv = bias[col];
        #pragma unroll
        for (int mt = 0; mt < 4; ++mt) {
            const int rb = row0 + mt * 16 + q * 4;
            #pragma unroll
            for (int e = 0; e < 4; ++e)
                out[(size_t)(rb + e) * OUT_DIM + col] = acc[mt][nt][e] + bv;
        }
    }
}

extern "C" void kernel_launch(void* const* d_in, const int* in_sizes, int n_in,
                              void* d_out, int out_size, void* d_ws, size_t ws_size,
                              hipStream_t stream)
{
    const float* x    = (const float*)d_in[0];
    // d_in[1] = grid (linspace(-2,2,8)) — folded into constants
    const float* sw   = (const float*)d_in[2];
    const float* bw   = (const float*)d_in[3];
    const float* bias = (const float*)d_in[4];
    float* out = (float*)d_out;

    const size_t bt_bytes = (size_t)OUT_DIM * K_TOT * sizeof(unsigned short);
    if (ws_size >= bt_bytes) {
        unsigned short* Btf = (unsigned short*)d_ws;
        prep_kernel<<<dim3(NKTILE / 4, OUT_DIM / 16), 256, 0, stream>>>(sw, bw, Btf);
        kan_kernel<true><<<dim3(512), 256, 0, stream>>>(
            x, Btf, sw, bw, bias, out);
    } else {
        kan_kernel<false><<<dim3(512), 256, 0, stream>>>(
            x, nullptr, sw, bw, bias, out);
    }
}